// Round 7
// baseline (1047.109 us; speedup 1.0000x reference)
//
#include <hip/hip_runtime.h>
#include <math.h>

// ======== coarse-bucket counting sort (128 nodes/bucket) + LDS aggregation ========
// R6 lesson: fine (per-node) CSR sortscatter is pinned at a scattered-write floor:
// 25.6MB payload -> 107MB HBM writes (8B stores, adjacent slots from different
// XCDs, never merged). Coarse 128-node buckets: single-pass build (vs 13x2 passes),
// ~4-entry runs (~2x amp), and aggregation becomes bucket-local in LDS with fused
// epilogues (no k_out / k_deg_dv / relu passes).
#define BS   128          // nodes per bucket
#define BSL  7
#define NBLK 1024         // edge-chunk blocks for count/scatter

typedef unsigned int uint;

// ---- pass 1: per-block histogram of bucket ids (single pass over edges) ----
__global__ __launch_bounds__(256) void k_bcount(const int* __restrict__ col,
                                                uint* __restrict__ cnt,
                                                int E, int NB, int chunk) {
    __shared__ uint bins[1024];
    for (int i = threadIdx.x; i < NB; i += 256) bins[i] = 0u;
    __syncthreads();
    int e0 = blockIdx.x * chunk, e1 = min(E, e0 + chunk);
    for (int e = e0 + threadIdx.x * 4; e < e1; e += 1024) {
        int4 c4;
        if (e + 3 < e1) c4 = *(const int4*)(col + e);
        else {
            c4.x = col[e];
            c4.y = (e + 1 < e1) ? col[e + 1] : -1;
            c4.z = (e + 2 < e1) ? col[e + 2] : -1;
            c4.w = (e + 3 < e1) ? col[e + 3] : -1;
        }
        if (c4.x >= 0) atomicAdd(&bins[c4.x >> BSL], 1u);
        if (c4.y >= 0) atomicAdd(&bins[c4.y >> BSL], 1u);
        if (c4.z >= 0) atomicAdd(&bins[c4.z >> BSL], 1u);
        if (c4.w >= 0) atomicAdd(&bins[c4.w >> BSL], 1u);
    }
    __syncthreads();
    for (int i = threadIdx.x; i < NB; i += 256)
        cnt[(size_t)i * NBLK + blockIdx.x] = bins[i];
}

// ---- pass 2: per bucket, exclusive scan over its NBLK block-counts + total ----
__global__ __launch_bounds__(256) void k_bprefix(uint* __restrict__ cnt,
                                                 uint* __restrict__ tot) {
    __shared__ uint s[256];
    uint* q = cnt + (size_t)blockIdx.x * NBLK;
    int t = threadIdx.x;
    uint v0 = q[t * 4], v1 = q[t * 4 + 1], v2 = q[t * 4 + 2], v3 = q[t * 4 + 3];
    uint s4 = v0 + v1 + v2 + v3;
    s[t] = s4;
    __syncthreads();
    for (int off = 1; off < 256; off <<= 1) {
        uint x = (t >= off) ? s[t - off] : 0u;
        __syncthreads();
        s[t] += x;
        __syncthreads();
    }
    uint excl = s[t] - s4;
    q[t * 4] = excl; q[t * 4 + 1] = excl + v0;
    q[t * 4 + 2] = excl + v0 + v1; q[t * 4 + 3] = excl + v0 + v1 + v2;
    if (t == 255) tot[blockIdx.x] = s[255];
}

// ---- pass 3: exclusive scan of bucket totals -> bbase[0..NB], bbase[NB]=E ----
__global__ __launch_bounds__(256) void k_scanT(const uint* __restrict__ tot,
                                               uint* __restrict__ bbase, int NB) {
    __shared__ uint s[256];
    __shared__ uint carry;
    int t = threadIdx.x;
    if (t == 0) carry = 0;
    __syncthreads();
    for (int base = 0; base < NB; base += 256) {
        int i = base + t;
        uint v = (i < NB) ? tot[i] : 0u;
        s[t] = v;
        __syncthreads();
        for (int off = 1; off < 256; off <<= 1) {
            uint x = (t >= off) ? s[t - off] : 0u;
            __syncthreads();
            s[t] += x;
            __syncthreads();
        }
        uint c = carry;
        if (i < NB) bbase[i] = c + s[t] - v;
        __syncthreads();
        if (t == 255) carry = c + s[255];
        __syncthreads();
    }
    if (t == 0) bbase[NB] = carry;
}

// ---- pass 4: scatter edges to bucket-sorted order; entry=(row<<7|col_local, w) ----
__global__ __launch_bounds__(256) void k_bscatter(const int* __restrict__ row,
        const int* __restrict__ col, const float* __restrict__ w,
        const uint* __restrict__ cnt, const uint* __restrict__ bbase,
        int2* __restrict__ sorted, int E, int NB, int chunk) {
    __shared__ uint cur[1024];
    for (int i = threadIdx.x; i < NB; i += 256)
        cur[i] = bbase[i] + cnt[(size_t)i * NBLK + blockIdx.x];
    __syncthreads();
    int e0 = blockIdx.x * chunk, e1 = min(E, e0 + chunk);
    for (int e = e0 + threadIdx.x * 4; e < e1; e += 1024) {
        int4 c4, r4;
        float4 w4;
        if (e + 3 < e1) {
            c4 = *(const int4*)(col + e);
            r4 = *(const int4*)(row + e);
            w4 = *(const float4*)(w + e);
        } else {
            c4.x = col[e]; r4.x = row[e]; w4.x = w[e];
            c4.y = (e + 1 < e1) ? col[e + 1] : -1; r4.y = (e + 1 < e1) ? row[e + 1] : 0;
            w4.y = (e + 1 < e1) ? w[e + 1] : 0.f;
            c4.z = (e + 2 < e1) ? col[e + 2] : -1; r4.z = (e + 2 < e1) ? row[e + 2] : 0;
            w4.z = (e + 2 < e1) ? w[e + 2] : 0.f;
            c4.w = -1; r4.w = 0; w4.w = 0.f;
        }
        int cc[4] = {c4.x, c4.y, c4.z, c4.w};
        int rr[4] = {r4.x, r4.y, r4.z, r4.w};
        float ww[4] = {w4.x, w4.y, w4.z, w4.w};
#pragma unroll
        for (int k = 0; k < 4; k++) {
            if (cc[k] >= 0) {
                uint slot = atomicAdd(&cur[cc[k] >> BSL], 1u);
                sorted[slot] = make_int2((rr[k] << BSL) | (cc[k] & (BS - 1)),
                                         __float_as_int(ww[k]));
            }
        }
    }
}

// ---- dv = rsqrt(1 + per-node w sum), one block per bucket ----
__global__ __launch_bounds__(256) void k_deg(const int2* __restrict__ sorted,
        const uint* __restrict__ bbase, float* __restrict__ dv, int N) {
    __shared__ float wa[BS];
    int b = blockIdx.x, t = threadIdx.x;
    if (t < BS) wa[t] = 0.f;
    __syncthreads();
    uint s0 = bbase[b], s1 = bbase[b + 1];
    for (uint k = s0 + t; k < s1; k += 256) {
        int2 v = sorted[k];
        atomicAdd(&wa[v.x & (BS - 1)], __int_as_float(v.y));
    }
    __syncthreads();
    if (t < BS) {
        int n = (b << BSL) + t;
        if (n < N) dv[n] = rsqrtf(1.f + wa[t]);
    }
}

// ---------------- x @ W1  (N x 256 @ 256 x 16), proven R4 version ----------------
__global__ __launch_bounds__(256) void k_xw1(const float* __restrict__ x,
                                             const float* __restrict__ W1,
                                             float* __restrict__ h, int N) {
    __shared__ float wsh[256 * 16];        // W1, then reused as reduction buffer
    int t = threadIdx.x;
    const float4* w4 = (const float4*)W1;
    float4* wsh4 = (float4*)wsh;
#pragma unroll
    for (int i = 0; i < 4; i++) wsh4[t + i * 256] = w4[t + i * 256];

    int lane = t & 63, kq = t >> 6;
    int r = blockIdx.x * 64 + lane;
    float acc[16];
#pragma unroll
    for (int j = 0; j < 16; j++) acc[j] = 0.f;
    __syncthreads();

    if (r < N) {
        const float4* xr = (const float4*)(x + (size_t)r * 256 + kq * 64);
#pragma unroll 4
        for (int k4 = 0; k4 < 16; k4++) {
            float4 xv = xr[k4];
            int kb = (kq * 64 + k4 * 4) * 16;
#pragma unroll
            for (int kk = 0; kk < 4; kk++) {
                float xs = (&xv.x)[kk];
                const float4* wrow = (const float4*)&wsh[kb + kk * 16];
#pragma unroll
                for (int jq = 0; jq < 4; jq++) {
                    float4 wv = wrow[jq];
                    acc[jq * 4 + 0] = fmaf(xs, wv.x, acc[jq * 4 + 0]);
                    acc[jq * 4 + 1] = fmaf(xs, wv.y, acc[jq * 4 + 1]);
                    acc[jq * 4 + 2] = fmaf(xs, wv.z, acc[jq * 4 + 2]);
                    acc[jq * 4 + 3] = fmaf(xs, wv.w, acc[jq * 4 + 3]);
                }
            }
        }
    }
    __syncthreads();
    if (kq) {
#pragma unroll
        for (int j = 0; j < 16; j++) wsh[((kq - 1) * 64 + lane) * 17 + j] = acc[j];
    }
    __syncthreads();
    if (kq == 0 && r < N) {
#pragma unroll
        for (int j = 0; j < 16; j++)
            acc[j] += wsh[lane * 17 + j] + wsh[(64 + lane) * 17 + j]
                    + wsh[(128 + lane) * 17 + j];
        float4* ho = (float4*)(h + (size_t)r * 16);
#pragma unroll
        for (int jq = 0; jq < 4; jq++)
            ho[jq] = make_float4(acc[jq * 4], acc[jq * 4 + 1],
                                 acc[jq * 4 + 2], acc[jq * 4 + 3]);
    }
}

// ---- layer1: block per bucket; LDS 128x16 acc; fused self+bias+relu ----
__global__ __launch_bounds__(256) void k_agg1(const int2* __restrict__ sorted,
        const uint* __restrict__ bbase, const float* __restrict__ dv,
        const float* __restrict__ h, const float* __restrict__ b1,
        float* __restrict__ h1, int N) {
    __shared__ float acc[BS * 16];
    __shared__ float dvl[BS];
    int b = blockIdx.x, t = threadIdx.x;
    for (int i = t; i < BS * 16; i += 256) acc[i] = 0.f;
    if (t < BS) {
        int n = (b << BSL) + t;
        dvl[t] = (n < N) ? dv[n] : 0.f;
    }
    __syncthreads();
    uint s0 = bbase[b], s1 = bbase[b + 1];
    for (uint k = s0 + t; k < s1; k += 256) {
        int2 v = sorted[k];
        int r = ((uint)v.x) >> BSL, lo = v.x & (BS - 1);
        float nr = dv[r] * __int_as_float(v.y) * dvl[lo];
        const float4* hr = (const float4*)(h + (size_t)r * 16);
        float4 h0 = hr[0], h1v = hr[1], h2 = hr[2], h3 = hr[3];
        float* ap = &acc[lo * 16];
        atomicAdd(ap + 0, nr * h0.x);  atomicAdd(ap + 1, nr * h0.y);
        atomicAdd(ap + 2, nr * h0.z);  atomicAdd(ap + 3, nr * h0.w);
        atomicAdd(ap + 4, nr * h1v.x); atomicAdd(ap + 5, nr * h1v.y);
        atomicAdd(ap + 6, nr * h1v.z); atomicAdd(ap + 7, nr * h1v.w);
        atomicAdd(ap + 8, nr * h2.x);  atomicAdd(ap + 9, nr * h2.y);
        atomicAdd(ap + 10, nr * h2.z); atomicAdd(ap + 11, nr * h2.w);
        atomicAdd(ap + 12, nr * h3.x); atomicAdd(ap + 13, nr * h3.y);
        atomicAdd(ap + 14, nr * h3.z); atomicAdd(ap + 15, nr * h3.w);
    }
    __syncthreads();
    for (int i = t; i < BS * 16; i += 256) {
        int lo = i >> 4, j = i & 15;
        int n = (b << BSL) + lo;
        if (n < N) {
            float val = acc[i] + dvl[lo] * dvl[lo] * h[(size_t)n * 16 + j] + b1[j];
            h1[(size_t)n * 16 + j] = fmaxf(val, 0.f);
        }
    }
}

// ---- layer2: block per bucket; fused self + @W2 + b2 + log_softmax ----
__global__ __launch_bounds__(256) void k_agg2out(const int2* __restrict__ sorted,
        const uint* __restrict__ bbase, const float* __restrict__ dv,
        const float* __restrict__ h1, const float* __restrict__ W2,
        const float* __restrict__ b2, float* __restrict__ out, int N) {
    __shared__ float acc[BS * 16];
    __shared__ float dvl[BS];
    __shared__ float w2s[16 * 40];
    __shared__ float b2s[40];
    int b = blockIdx.x, t = threadIdx.x;
    for (int i = t; i < BS * 16; i += 256) acc[i] = 0.f;
    for (int i = t; i < 640; i += 256) w2s[i] = W2[i];
    if (t < 40) b2s[t] = b2[t];
    if (t < BS) {
        int n = (b << BSL) + t;
        dvl[t] = (n < N) ? dv[n] : 0.f;
    }
    __syncthreads();
    uint s0 = bbase[b], s1 = bbase[b + 1];
    for (uint k = s0 + t; k < s1; k += 256) {
        int2 v = sorted[k];
        int r = ((uint)v.x) >> BSL, lo = v.x & (BS - 1);
        float nr = dv[r] * __int_as_float(v.y) * dvl[lo];
        const float4* hr = (const float4*)(h1 + (size_t)r * 16);
        float4 h0 = hr[0], h1v = hr[1], h2 = hr[2], h3 = hr[3];
        float* ap = &acc[lo * 16];
        atomicAdd(ap + 0, nr * h0.x);  atomicAdd(ap + 1, nr * h0.y);
        atomicAdd(ap + 2, nr * h0.z);  atomicAdd(ap + 3, nr * h0.w);
        atomicAdd(ap + 4, nr * h1v.x); atomicAdd(ap + 5, nr * h1v.y);
        atomicAdd(ap + 6, nr * h1v.z); atomicAdd(ap + 7, nr * h1v.w);
        atomicAdd(ap + 8, nr * h2.x);  atomicAdd(ap + 9, nr * h2.y);
        atomicAdd(ap + 10, nr * h2.z); atomicAdd(ap + 11, nr * h2.w);
        atomicAdd(ap + 12, nr * h3.x); atomicAdd(ap + 13, nr * h3.y);
        atomicAdd(ap + 14, nr * h3.z); atomicAdd(ap + 15, nr * h3.w);
    }
    __syncthreads();
    for (int i = t; i < BS * 16; i += 256) {          // add self-loop term
        int lo = i >> 4, j = i & 15;
        int n = (b << BSL) + lo;
        if (n < N) acc[i] += dvl[lo] * dvl[lo] * h1[(size_t)n * 16 + j];
    }
    __syncthreads();
    int lane = t & 63, wv = t >> 6;
    for (int lo = wv; lo < BS; lo += 4) {             // wave per node
        int n = (b << BSL) + lo;
        if (n >= N) continue;                          // uniform per wave
        float logit = -INFINITY;
        if (lane < 40) {
            logit = b2s[lane];
#pragma unroll
            for (int q = 0; q < 16; q++) logit += acc[lo * 16 + q] * w2s[q * 40 + lane];
        }
        float m = logit;
#pragma unroll
        for (int off = 32; off; off >>= 1) m = fmaxf(m, __shfl_xor(m, off));
        float ex = (lane < 40) ? expf(logit - m) : 0.f;
        float ssum = ex;
#pragma unroll
        for (int off = 32; off; off >>= 1) ssum += __shfl_xor(ssum, off);
        if (lane < 40) out[(size_t)n * 40 + lane] = logit - m - logf(ssum);
    }
}

extern "C" void kernel_launch(void* const* d_in, const int* in_sizes, int n_in,
                              void* d_out, int out_size, void* d_ws, size_t ws_size,
                              hipStream_t stream) {
    const float* x  = (const float*)d_in[0];
    const int*   ei = (const int*)d_in[1];
    const float* ew = (const float*)d_in[2];
    const float* W1 = (const float*)d_in[3];
    const float* b1 = (const float*)d_in[4];
    const float* W2 = (const float*)d_in[5];
    const float* b2 = (const float*)d_in[6];
    float* out = (float*)d_out;

    int N = in_sizes[0] / 256;
    int E = in_sizes[2];
    const int* row = ei;
    const int* col = ei + E;

    int NB = (N + BS - 1) >> BSL;                 // 782 buckets
    int chunk = (((E + NBLK - 1) / NBLK) + 3) & ~3;

    // workspace (u32 units), ~34MB total:
    //   sorted 2E | cnt NB*NBLK | tot NB | bbase NB+1 | dv N | h 16N | h1 16N
    uint* ws32 = (uint*)d_ws;
    int2* sorted = (int2*)ws32;
    uint* cnt   = ws32 + 2 * (size_t)E;
    uint* tot   = cnt + (size_t)NB * NBLK;
    uint* bbase = tot + NB;
    float* dv   = (float*)(bbase + NB + 1);
    float* h    = dv + N;
    float* h1   = h + (size_t)N * 16;

    k_bcount  <<<NBLK, 256, 0, stream>>>(col, cnt, E, NB, chunk);
    k_bprefix <<<NB, 256, 0, stream>>>(cnt, tot);
    k_scanT   <<<1, 256, 0, stream>>>(tot, bbase, NB);
    k_bscatter<<<NBLK, 256, 0, stream>>>(row, col, ew, cnt, bbase, sorted, E, NB, chunk);
    k_deg     <<<NB, 256, 0, stream>>>(sorted, bbase, dv, N);
    k_xw1     <<<(N + 63) / 64, 256, 0, stream>>>(x, W1, h, N);
    k_agg1    <<<NB, 256, 0, stream>>>(sorted, bbase, dv, h, b1, h1, N);
    k_agg2out <<<NB, 256, 0, stream>>>(sorted, bbase, dv, h1, W2, b2, out, N);
}

// Round 8
// 542.570 us; speedup vs baseline: 1.9299x; 1.9299x over previous
//
#include <hip/hip_runtime.h>
#include <math.h>

// ============ two-level counting sort (bucket, then in-bucket) + CSR gather ============
// R6: fine 13-pass CSR sort cost 277us (cnt_hist 110 + sortscatter 117 w/ 4x write amp
//     + scans), gathers+xw1 ~200 -> 608us total.
// R7: coarse-bucket AGGREGATION failed (379us/layer: 782-block grid cap + 16 serial
//     2-bank LDS atomics/edge), but single-pass bucket SORT kernels were cheap.
// R8: bucket sort (single pass) + per-bucket fine sort in LDS (dense in-bucket writes
//     -> no write amp; fuses deg/dv + CSR offsets), then R6's proven gathers unchanged.
#define BS   128          // nodes per bucket
#define BSL  7
#define NBLK 1024         // edge-chunk blocks for count/scatter

typedef unsigned int uint;

// ---- pass 1: per-block histogram of bucket ids (single pass over edges) ----
__global__ __launch_bounds__(256) void k_bcount(const int* __restrict__ col,
                                                uint* __restrict__ cnt,
                                                int E, int NB, int chunk) {
    __shared__ uint bins[1024];
    for (int i = threadIdx.x; i < NB; i += 256) bins[i] = 0u;
    __syncthreads();
    int e0 = blockIdx.x * chunk, e1 = min(E, e0 + chunk);
    for (int e = e0 + threadIdx.x * 4; e < e1; e += 1024) {
        int4 c4;
        if (e + 3 < e1) c4 = *(const int4*)(col + e);
        else {
            c4.x = col[e];
            c4.y = (e + 1 < e1) ? col[e + 1] : -1;
            c4.z = (e + 2 < e1) ? col[e + 2] : -1;
            c4.w = (e + 3 < e1) ? col[e + 3] : -1;
        }
        if (c4.x >= 0) atomicAdd(&bins[c4.x >> BSL], 1u);
        if (c4.y >= 0) atomicAdd(&bins[c4.y >> BSL], 1u);
        if (c4.z >= 0) atomicAdd(&bins[c4.z >> BSL], 1u);
        if (c4.w >= 0) atomicAdd(&bins[c4.w >> BSL], 1u);
    }
    __syncthreads();
    for (int i = threadIdx.x; i < NB; i += 256)
        cnt[(size_t)i * NBLK + blockIdx.x] = bins[i];
}

// ---- pass 2: per bucket, exclusive scan over its NBLK block-counts + total ----
__global__ __launch_bounds__(256) void k_bprefix(uint* __restrict__ cnt,
                                                 uint* __restrict__ tot) {
    __shared__ uint s[256];
    uint* q = cnt + (size_t)blockIdx.x * NBLK;
    int t = threadIdx.x;
    uint v0 = q[t * 4], v1 = q[t * 4 + 1], v2 = q[t * 4 + 2], v3 = q[t * 4 + 3];
    uint s4 = v0 + v1 + v2 + v3;
    s[t] = s4;
    __syncthreads();
    for (int off = 1; off < 256; off <<= 1) {
        uint x = (t >= off) ? s[t - off] : 0u;
        __syncthreads();
        s[t] += x;
        __syncthreads();
    }
    uint excl = s[t] - s4;
    q[t * 4] = excl; q[t * 4 + 1] = excl + v0;
    q[t * 4 + 2] = excl + v0 + v1; q[t * 4 + 3] = excl + v0 + v1 + v2;
    if (t == 255) tot[blockIdx.x] = s[255];
}

// ---- pass 3: exclusive scan of bucket totals -> bbase[0..NB], bbase[NB]=E ----
__global__ __launch_bounds__(256) void k_scanT(const uint* __restrict__ tot,
                                               uint* __restrict__ bbase, int NB) {
    __shared__ uint s[256];
    __shared__ uint carry;
    int t = threadIdx.x;
    if (t == 0) carry = 0;
    __syncthreads();
    for (int base = 0; base < NB; base += 256) {
        int i = base + t;
        uint v = (i < NB) ? tot[i] : 0u;
        s[t] = v;
        __syncthreads();
        for (int off = 1; off < 256; off <<= 1) {
            uint x = (t >= off) ? s[t - off] : 0u;
            __syncthreads();
            s[t] += x;
            __syncthreads();
        }
        uint c = carry;
        if (i < NB) bbase[i] = c + s[t] - v;
        __syncthreads();
        if (t == 255) carry = c + s[255];
        __syncthreads();
    }
    if (t == 0) bbase[NB] = carry;
}

// ---- pass 4: scatter edges to bucket order; entry=(row<<7|col_local, w) ----
__global__ __launch_bounds__(256) void k_bscatter(const int* __restrict__ row,
        const int* __restrict__ col, const float* __restrict__ w,
        const uint* __restrict__ cnt, const uint* __restrict__ bbase,
        int2* __restrict__ bsorted, int E, int NB, int chunk) {
    __shared__ uint cur[1024];
    for (int i = threadIdx.x; i < NB; i += 256)
        cur[i] = bbase[i] + cnt[(size_t)i * NBLK + blockIdx.x];
    __syncthreads();
    int e0 = blockIdx.x * chunk, e1 = min(E, e0 + chunk);
    for (int e = e0 + threadIdx.x * 4; e < e1; e += 1024) {
        int4 c4, r4;
        float4 w4;
        if (e + 3 < e1) {
            c4 = *(const int4*)(col + e);
            r4 = *(const int4*)(row + e);
            w4 = *(const float4*)(w + e);
        } else {
            c4.x = col[e]; r4.x = row[e]; w4.x = w[e];
            c4.y = (e + 1 < e1) ? col[e + 1] : -1; r4.y = (e + 1 < e1) ? row[e + 1] : 0;
            w4.y = (e + 1 < e1) ? w[e + 1] : 0.f;
            c4.z = (e + 2 < e1) ? col[e + 2] : -1; r4.z = (e + 2 < e1) ? row[e + 2] : 0;
            w4.z = (e + 2 < e1) ? w[e + 2] : 0.f;
            c4.w = -1; r4.w = 0; w4.w = 0.f;
        }
        int cc[4] = {c4.x, c4.y, c4.z, c4.w};
        int rr[4] = {r4.x, r4.y, r4.z, r4.w};
        float ww[4] = {w4.x, w4.y, w4.z, w4.w};
#pragma unroll
        for (int k = 0; k < 4; k++) {
            if (cc[k] >= 0) {
                uint slot = atomicAdd(&cur[cc[k] >> BSL], 1u);
                bsorted[slot] = make_int2((rr[k] << BSL) | (cc[k] & (BS - 1)),
                                          __float_as_int(ww[k]));
            }
        }
    }
}

// ---- pass 5: fine sort within bucket (LDS hist+cursors); fuses dv + CSR offsets.
// Writes are 8B scattered but DENSE within the bucket's ~32KB region -> L2 merges
// to full lines (no 4x HBM write amp, the R6 sortscatter killer).
__global__ __launch_bounds__(256) void k_fsort(const int2* __restrict__ bsorted,
        const uint* __restrict__ bbase, int2* __restrict__ fsorted,
        uint* __restrict__ nodeoff, float* __restrict__ dv, int N) {
    __shared__ uint hist[BS];
    __shared__ float wa[BS];
    __shared__ uint cur[BS];
    int b = blockIdx.x, t = threadIdx.x;
    if (t < BS) { hist[t] = 0u; wa[t] = 0.f; }
    __syncthreads();
    uint s0 = bbase[b], s1 = bbase[b + 1];
    for (uint k = s0 + t; k < s1; k += 256) {
        int2 v = bsorted[k];
        int lo = v.x & (BS - 1);
        atomicAdd(&hist[lo], 1u);
        atomicAdd(&wa[lo], __int_as_float(v.y));
    }
    __syncthreads();
    uint vv = (t < BS) ? hist[t] : 0u;          // Hillis-Steele over 128
    for (int off = 1; off < BS; off <<= 1) {
        uint x = (t < BS && t >= off) ? hist[t - off] : 0u;
        __syncthreads();
        if (t < BS) hist[t] += x;
        __syncthreads();
    }
    if (t < BS) {
        uint base = s0 + (hist[t] - vv);        // exclusive prefix
        cur[t] = base;
        nodeoff[(b << BSL) + t] = base;
        int n = (b << BSL) + t;
        if (n < N) dv[n] = rsqrtf(1.f + wa[t]); // self-loop weight 1
    }
    __syncthreads();
    for (uint k = s0 + t; k < s1; k += 256) {
        int2 v = bsorted[k];
        int lo = v.x & (BS - 1);
        uint slot = atomicAdd(&cur[lo], 1u);
        fsorted[slot] = make_int2(((uint)v.x) >> BSL, v.y);   // plain row
    }
}

// ---------------- x @ W1  (N x 256 @ 256 x 16), proven R4 version ----------------
__global__ __launch_bounds__(256) void k_xw1(const float* __restrict__ x,
                                             const float* __restrict__ W1,
                                             float* __restrict__ h, int N) {
    __shared__ float wsh[256 * 16];        // W1, then reused as reduction buffer
    int t = threadIdx.x;
    const float4* w4 = (const float4*)W1;
    float4* wsh4 = (float4*)wsh;
#pragma unroll
    for (int i = 0; i < 4; i++) wsh4[t + i * 256] = w4[t + i * 256];

    int lane = t & 63, kq = t >> 6;
    int r = blockIdx.x * 64 + lane;
    float acc[16];
#pragma unroll
    for (int j = 0; j < 16; j++) acc[j] = 0.f;
    __syncthreads();

    if (r < N) {
        const float4* xr = (const float4*)(x + (size_t)r * 256 + kq * 64);
#pragma unroll 4
        for (int k4 = 0; k4 < 16; k4++) {
            float4 xv = xr[k4];
            int kb = (kq * 64 + k4 * 4) * 16;
#pragma unroll
            for (int kk = 0; kk < 4; kk++) {
                float xs = (&xv.x)[kk];
                const float4* wrow = (const float4*)&wsh[kb + kk * 16];
#pragma unroll
                for (int jq = 0; jq < 4; jq++) {
                    float4 wv = wrow[jq];
                    acc[jq * 4 + 0] = fmaf(xs, wv.x, acc[jq * 4 + 0]);
                    acc[jq * 4 + 1] = fmaf(xs, wv.y, acc[jq * 4 + 1]);
                    acc[jq * 4 + 2] = fmaf(xs, wv.z, acc[jq * 4 + 2]);
                    acc[jq * 4 + 3] = fmaf(xs, wv.w, acc[jq * 4 + 3]);
                }
            }
        }
    }
    __syncthreads();
    if (kq) {
#pragma unroll
        for (int j = 0; j < 16; j++) wsh[((kq - 1) * 64 + lane) * 17 + j] = acc[j];
    }
    __syncthreads();
    if (kq == 0 && r < N) {
#pragma unroll
        for (int j = 0; j < 16; j++)
            acc[j] += wsh[lane * 17 + j] + wsh[(64 + lane) * 17 + j]
                    + wsh[(128 + lane) * 17 + j];
        float4* ho = (float4*)(h + (size_t)r * 16);
#pragma unroll
        for (int jq = 0; jq < 4; jq++)
            ho[jq] = make_float4(acc[jq * 4], acc[jq * 4 + 1],
                                 acc[jq * 4 + 2], acc[jq * 4 + 3]);
    }
}

// ---- layer1: h1 = relu(self + gather + b1); wave per node (proven R6) ----
__global__ __launch_bounds__(256) void k_gather_l1(const int2* __restrict__ sorted,
        const uint* __restrict__ no, const float* __restrict__ dv,
        const float* __restrict__ h, const float* __restrict__ b1,
        float* __restrict__ ho, int N) {
    int wave = threadIdx.x >> 6;
    int node = blockIdx.x * 4 + wave;
    if (node >= N) return;
    int lane = threadIdx.x & 63;
    int es = lane >> 4, j = lane & 15;
    uint s0 = no[node], s1 = no[node + 1];
    float dvn = dv[node];
    float acc = 0.f;
    for (uint k = s0 + es; k < s1; k += 4) {
        int2 pr = sorted[k];
        float nr = dv[pr.x] * __int_as_float(pr.y) * dvn;
        acc += nr * h[(size_t)pr.x * 16 + j];
    }
    acc += __shfl_xor(acc, 16);
    acc += __shfl_xor(acc, 32);
    acc += dvn * dvn * h[(size_t)node * 16 + j] + b1[j];
    acc = fmaxf(acc, 0.f);
    if (es == 0) ho[(size_t)node * 16 + j] = acc;
}

// ---- layer2 fused with @W2 + b2 + log_softmax epilogue (proven R6) ----
__global__ __launch_bounds__(256) void k_gather_l2out(const int2* __restrict__ sorted,
        const uint* __restrict__ no, const float* __restrict__ dv,
        const float* __restrict__ h, const float* __restrict__ W2,
        const float* __restrict__ b2, float* __restrict__ out, int N) {
    int wave = threadIdx.x >> 6;
    int node = blockIdx.x * 4 + wave;
    if (node >= N) return;
    int lane = threadIdx.x & 63;
    int es = lane >> 4, j = lane & 15;
    uint s0 = no[node], s1 = no[node + 1];
    float dvn = dv[node];
    float acc = 0.f;
    for (uint k = s0 + es; k < s1; k += 4) {
        int2 pr = sorted[k];
        float nr = dv[pr.x] * __int_as_float(pr.y) * dvn;
        acc += nr * h[(size_t)pr.x * 16 + j];
    }
    acc += __shfl_xor(acc, 16);
    acc += __shfl_xor(acc, 32);
    acc += dvn * dvn * h[(size_t)node * 16 + j];   // agg2_j (replicated over es)

    float aj[16];
#pragma unroll
    for (int q = 0; q < 16; q++) aj[q] = __shfl(acc, q);
    float logit = -INFINITY;
    if (lane < 40) {
        logit = b2[lane];
#pragma unroll
        for (int q = 0; q < 16; q++) logit += aj[q] * W2[q * 40 + lane];
    }
    float m = logit;
#pragma unroll
    for (int off = 32; off; off >>= 1) m = fmaxf(m, __shfl_xor(m, off));
    float ex = (lane < 40) ? expf(logit - m) : 0.f;
    float ssum = ex;
#pragma unroll
    for (int off = 32; off; off >>= 1) ssum += __shfl_xor(ssum, off);
    if (lane < 40) out[(size_t)node * 40 + lane] = logit - m - logf(ssum);
}

extern "C" void kernel_launch(void* const* d_in, const int* in_sizes, int n_in,
                              void* d_out, int out_size, void* d_ws, size_t ws_size,
                              hipStream_t stream) {
    const float* x  = (const float*)d_in[0];
    const int*   ei = (const int*)d_in[1];
    const float* ew = (const float*)d_in[2];
    const float* W1 = (const float*)d_in[3];
    const float* b1 = (const float*)d_in[4];
    const float* W2 = (const float*)d_in[5];
    const float* b2 = (const float*)d_in[6];
    float* out = (float*)d_out;

    int N = in_sizes[0] / 256;
    int E = in_sizes[2];
    const int* row = ei;
    const int* col = ei + E;

    int NB = (N + BS - 1) >> BSL;                 // 782 buckets
    int chunk = (((E + NBLK - 1) / NBLK) + 3) & ~3;

    // workspace (u32 units), peak ~55MB (= proven R4/R6 peak):
    //   fsorted 2E | bsorted 2E (dead after fsort -> reused for h, h1)
    //   | cnt NB*NBLK | tot NB | bbase NB+1 | nodeoff NB*BS+1 | dv N
    uint* ws32 = (uint*)d_ws;
    int2* fsorted = (int2*)ws32;
    int2* bsorted = (int2*)(ws32 + 2 * (size_t)E);
    uint* cnt     = ws32 + 4 * (size_t)E;
    uint* tot     = cnt + (size_t)NB * NBLK;
    uint* bbase   = tot + NB;
    uint* nodeoff = bbase + NB + 1;
    float* dv     = (float*)(nodeoff + (size_t)NB * BS + 1);
    float* h      = (float*)bsorted;              // reuse after k_fsort
    float* h1     = h + (size_t)N * 16;

    k_bcount  <<<NBLK, 256, 0, stream>>>(col, cnt, E, NB, chunk);
    k_bprefix <<<NB, 256, 0, stream>>>(cnt, tot);
    k_scanT   <<<1, 256, 0, stream>>>(tot, bbase, NB);
    k_bscatter<<<NBLK, 256, 0, stream>>>(row, col, ew, cnt, bbase, bsorted, E, NB, chunk);
    k_fsort   <<<NB, 256, 0, stream>>>(bsorted, bbase, fsorted, nodeoff, dv, N);
    k_xw1     <<<(N + 63) / 64, 256, 0, stream>>>(x, W1, h, N);
    k_gather_l1   <<<(N + 3) / 4, 256, 0, stream>>>(fsorted, nodeoff, dv, h, b1, h1, N);
    k_gather_l2out<<<(N + 3) / 4, 256, 0, stream>>>(fsorted, nodeoff, dv, h1, W2, b2, out, N);
}